// Round 11
// baseline (963.035 us; speedup 1.0000x reference)
//
#include <hip/hip_runtime.h>
#include <hip/hip_bf16.h>
#include <hip/hip_fp16.h>

#define B_    8192
#define D_    1024
#define H_    4096
#define DOUT_ 1024
#define E_    8
#define MAXR  17408   // 16384 assignments + 8*128 padding
#define NT256 72      // max 256-row tiles: sum ceil(pn_e/256) <= 64+8

typedef float    f32x4 __attribute__((ext_vector_type(4)));
typedef _Float16 f16x8 __attribute__((ext_vector_type(8)));
typedef unsigned short u16;
typedef u16      u16x8 __attribute__((ext_vector_type(8)));
typedef u16      u16x4 __attribute__((ext_vector_type(4)));
typedef unsigned int u32;

__device__ __forceinline__ u16 f2h_bits(float f) {
  _Float16 h = (_Float16)f;
  return __builtin_bit_cast(u16, h);
}

// tanh-form gelu (max abs err vs erf-gelu ~3e-4; threshold margin 4x)
__device__ __forceinline__ float gelu_f(float v) {
  float z = 0.7978845608028654f * (v + 0.044715f * v * v * v);
  float ez = __expf(2.f * z);
  float th = 1.f - 2.f / (ez + 1.f);
  return 0.5f * v * (1.f + th);
}

// ---- workspace layout (bytes) ----
#define OFF_TOPI 512                       // int[16384]
#define OFF_TOPW (OFF_TOPI + 65536)        // float[16384]
#define OFF_ATOK (OFF_TOPW + 65536)        // int[17408]
#define OFF_WSL  (OFF_ATOK + 69632)        // float[17408]
#define OFF_TMAP 280064                    // int[NT256] packed (e<<20|row0)
#define OFF_XG   524288                    // u16[17408*1024] f16 (dead after gemm1)
#define OFF_W1T  (OFF_XG + 35651584)       // u16[8*4096*1024] f16 (dead after gemm1)
#define OFF_W2T  OFF_XG                    // u16[8*1024*4096] f16, ALIASES Xg+W1t
#define OFF_HB   (OFF_W1T + 67108864)      // u16[17408*4096] f16
// end = 245,891,072 bytes

__global__ void k_zero_out(float* __restrict__ out) {
  size_t i = (size_t)(blockIdx.x * 256 + threadIdx.x) * 4;
  *(f32x4*)&out[i] = (f32x4){0.f, 0.f, 0.f, 0.f};
}

__global__ void k_init(int* __restrict__ atok, float* __restrict__ wslot,
                       int* __restrict__ meta) {
  int i = blockIdx.x * 256 + threadIdx.x;
  if (i < MAXR) { atok[i] = 0; wslot[i] = 0.f; }
  if (blockIdx.x == 0 && threadIdx.x < 64) meta[threadIdx.x] = 0;
}

__global__ __launch_bounds__(256) void k_gate(
    const float* __restrict__ x, const float* __restrict__ Wg,
    const float* __restrict__ bg, int* __restrict__ counts,
    float* __restrict__ usage, int* __restrict__ topi, float* __restrict__ topw) {
  __shared__ float su[E_];
  if (threadIdx.x < E_) su[threadIdx.x] = 0.f;
  __syncthreads();
  const int lane = threadIdx.x & 63;
  const int b = blockIdx.x * 4 + (threadIdx.x >> 6);
  float p[E_] = {0.f,0.f,0.f,0.f,0.f,0.f,0.f,0.f};
  #pragma unroll
  for (int j = 0; j < 4; ++j) {
    int d = j * 256 + lane * 4;
    float4 xv = *(const float4*)&x[(size_t)b * D_ + d];
    const float* wr = &Wg[(size_t)d * E_];
    #pragma unroll
    for (int c = 0; c < 4; ++c) {
      float xc = reinterpret_cast<const float*>(&xv)[c];
      #pragma unroll
      for (int e = 0; e < E_; ++e) p[e] += xc * wr[c * E_ + e];
    }
  }
  #pragma unroll
  for (int off = 32; off >= 1; off >>= 1)
    #pragma unroll
    for (int e = 0; e < E_; ++e) p[e] += __shfl_xor(p[e], off, 64);
  float mx = -1e30f;
  #pragma unroll
  for (int e = 0; e < E_; ++e) { p[e] += bg[e]; mx = fmaxf(mx, p[e]); }
  int i0 = 0; float l0 = p[0];
  #pragma unroll
  for (int e = 1; e < E_; ++e) if (p[e] > l0) { l0 = p[e]; i0 = e; }
  int i1 = -1; float l1 = -1e30f;
  #pragma unroll
  for (int e = 0; e < E_; ++e) if (e != i0 && p[e] > l1) { l1 = p[e]; i1 = e; }
  float s = 0.f;
  #pragma unroll
  for (int e = 0; e < E_; ++e) { p[e] = expf(p[e] - mx); s += p[e]; }
  float inv = 1.f / s;
  if (lane == 0) {
    float e0 = expf(l0 - mx), e1 = expf(l1 - mx);
    float wsum = e0 + e1;
    topi[b * 2] = i0; topi[b * 2 + 1] = i1;
    topw[b * 2] = e0 / wsum; topw[b * 2 + 1] = e1 / wsum;
    atomicAdd(&counts[i0], 1);
    atomicAdd(&counts[i1], 1);
    #pragma unroll
    for (int e = 0; e < E_; ++e) atomicAdd(&su[e], p[e] * inv);
  }
  __syncthreads();
  if (threadIdx.x < E_) atomicAdd(&usage[threadIdx.x], su[threadIdx.x]);
}

__global__ void k_scan_aux(const int* __restrict__ counts, int* __restrict__ offsets,
                           const float* __restrict__ usage, float* __restrict__ auxp,
                           int* __restrict__ tmap) {
  if (threadIdx.x == 0) {
    int off = 0;
    for (int e = 0; e < E_; ++e) { offsets[e] = off; off += (counts[e] + 127) & ~127; }
    offsets[E_] = off;
    // dense 256-row tile table (skew-proof)
    int nT = 0;
    for (int e = 0; e < E_; ++e) {
      int roff = offsets[e], pn = offsets[e + 1] - roff;
      for (int r0 = 0; r0 < pn; r0 += 256)
        tmap[nT++] = (e << 20) | (roff + r0);
    }
    for (int t = nT; t < NT256; ++t) tmap[t] = -1;
    float aux = 0.f;
    const float lu = logf(1.0f / (float)E_);
    for (int e = 0; e < E_; ++e) {
      float u = usage[e] * (1.0f / (float)B_);
      aux += u * lu - logf(u) * (1.0f / (float)E_);
    }
    *auxp = aux;
  }
}

__global__ void k_scatter(const int* __restrict__ topi, const float* __restrict__ topw,
                          const int* __restrict__ offsets, int* __restrict__ cursors,
                          int* __restrict__ atok, float* __restrict__ wslot) {
  int b = blockIdx.x * 256 + threadIdx.x;
  if (b >= B_) return;
  #pragma unroll
  for (int k = 0; k < 2; ++k) {
    int e = topi[b * 2 + k];
    int pos = atomicAdd(&cursors[e], 1);
    int slot = offsets[e] + pos;
    atok[slot] = b;
    wslot[slot] = topw[b * 2 + k];
  }
}

__global__ __launch_bounds__(256) void k_gather(const float* __restrict__ x,
                                                const int* __restrict__ atok,
                                                u16* __restrict__ Xg) {
  int slot = blockIdx.x;
  int tok = atok[slot];
  int c = threadIdx.x * 4;
  float4 v = *(const float4*)&x[(size_t)tok * D_ + c];
  const float* vf = reinterpret_cast<const float*>(&v);
  u16x4 o;
  o.x = f2h_bits(vf[0]); o.y = f2h_bits(vf[1]);
  o.z = f2h_bits(vf[2]); o.w = f2h_bits(vf[3]);
  *(u16x4*)&Xg[(size_t)slot * D_ + c] = o;
}

// convert + transpose: src [E][K][N] fp32  ->  dst [E][N][K] f16. 64x64 tiles.
__global__ __launch_bounds__(256) void k_cvt_t(const float* __restrict__ src,
                                               u16* __restrict__ dst, int K, int N) {
  const int e = blockIdx.z;
  const int kt = blockIdx.x * 64;
  const int nt = blockIdx.y * 64;
  __shared__ u16 t[64][68];
  const float* s = src + (size_t)e * K * N;
  u16* d = dst + (size_t)e * N * K;
  const int tr = threadIdx.x >> 4;
  const int tc = threadIdx.x & 15;
  #pragma unroll
  for (int i = 0; i < 4; ++i) {
    int k = tr + i * 16;
    float4 v = *(const float4*)&s[(size_t)(kt + k) * N + nt + tc * 4];
    t[k][tc*4+0] = f2h_bits(v.x); t[k][tc*4+1] = f2h_bits(v.y);
    t[k][tc*4+2] = f2h_bits(v.z); t[k][tc*4+3] = f2h_bits(v.w);
  }
  __syncthreads();
  #pragma unroll
  for (int i = 0; i < 4; ++i) {
    int n = tr + i * 16;
    u16x4 o;
    o.x = t[tc*4+0][n]; o.y = t[tc*4+1][n];
    o.z = t[tc*4+2][n]; o.w = t[tc*4+3][n];
    *(u16x4*)&d[(size_t)(nt + n) * K + kt + tc * 4] = o;
  }
}

#define GLDS(g, l) __builtin_amdgcn_global_load_lds( \
    (const u32 __attribute__((address_space(1)))*)(g), \
    (u32 __attribute__((address_space(3)))*)(l), 16, 0, 0)

// ==== 256x256 tile, BK=32, dbuf 64KB LDS, issue-early, 8 waves (2Mx4N) ====
// LDS: SM[32768] u16; A0@0 B0@8192 A1@16384 B1@24576. Buffer = 256 rows x 32 u16.
// XOR source-swizzle (R9-proven pair):
//   LDS[row][chunk] = src[row][chunk ^ ((row^(row>>2))&3)]  (16B chunks)
// 16 segments of 16 rows; seg = wid*2+c (wid 0..7); segment = 512 u16.
#define STG(LDK, kk, Aoff, Boff) do { \
  const int r_ = lane >> 2; \
  const int sc_ = ((lane & 3) ^ ((r_ ^ (r_ >> 2)) & 3)) * 8; \
  _Pragma("unroll") \
  for (int c = 0; c < 2; ++c) { \
    int seg = wid * 2 + c; \
    int rowA = seg * 16 + r_; if (rowA > Alim) rowA = Alim; \
    GLDS(Ap + (size_t)rowA * (LDK) + (kk) + sc_, SM + (Aoff) + seg * 512); \
    GLDS(Bp + (size_t)(seg * 16 + r_) * (LDK) + (kk) + sc_, SM + (Boff) + seg * 512); \
  } } while (0)

// wave-tile 128x64: 12 ds_read_b128 + 32 MFMA per BK=32 step
#define CMP(Aoff, Boff) do { \
  const int r15_ = lane & 15; \
  const int co_ = (((lane >> 4) ^ ((r15_ ^ (r15_ >> 2)) & 3)) * 8); \
  f16x8 af[8], bf[4]; \
  _Pragma("unroll") \
  for (int m = 0; m < 8; ++m) \
    af[m] = *(const f16x8*)&SM[(Aoff) + (wr * 128 + m * 16 + r15_) * 32 + co_]; \
  _Pragma("unroll") \
  for (int n = 0; n < 4; ++n) \
    bf[n] = *(const f16x8*)&SM[(Boff) + (wc * 64 + n * 16 + r15_) * 32 + co_]; \
  _Pragma("unroll") \
  for (int m = 0; m < 8; ++m) \
    _Pragma("unroll") \
    for (int n = 0; n < 4; ++n) \
      acc[m][n] = __builtin_amdgcn_mfma_f32_16x16x32_f16(af[m], bf[n], acc[m][n], 0, 0, 0); \
  } while (0)

// GEMM1: Hb[row][n] = gelu( Xg[row][:] @ W1t[e][n][:]^T + b1[e][n] )  (f16)
// Grid NT256*16; tile from device table (dense, skew-proof); nt minor (A reuse).
__global__ __launch_bounds__(512, 2) void k_gemm1(
    const u16* __restrict__ Xg, const u16* __restrict__ W1t,
    const float* __restrict__ b1, const int* __restrict__ offsets,
    const int* __restrict__ tmap, u16* __restrict__ Hb) {
  const int packed = tmap[blockIdx.x >> 4];
  if (packed < 0) return;
  const int e = packed >> 20;
  const int row0g = packed & 0xFFFFF;
  const int rend = offsets[e + 1];
  const int nt = blockIdx.x & 15;
  const int n0 = nt * 256;
  const int tid = threadIdx.x, lane = tid & 63, wid = tid >> 6;
  const int wr = wid >> 2, wc = wid & 3;     // 2M x 4N waves, wave-tile 128x64
  const int Alim = (MAXR - 1) - row0g;       // clamp A-rows inside workspace
  __shared__ __align__(16) u16 SM[32768];
  f32x4 acc[8][4] = {};
  const u16* Ap = Xg + (size_t)row0g * D_;
  const u16* Bp = W1t + (size_t)e * H_ * D_ + (size_t)n0 * D_;

  STG(D_, 0, 0, 8192);
  __syncthreads();
  for (int t = 0; t < 32; t += 2) {
    STG(D_, (t + 1) * 32, 16384, 24576);
    CMP(0, 8192);
    __syncthreads();
    if (t + 2 < 32) STG(D_, (t + 2) * 32, 0, 8192);
    CMP(16384, 24576);
    __syncthreads();
  }
  // epilogue: bias+gelu -> LDS (64 x 264, 528B rows, 16B-aligned) -> 16B stores
  const int rhi = (lane >> 4) * 4, cix = lane & 15;
  float bv[4];
  #pragma unroll
  for (int n = 0; n < 4; ++n) bv[n] = b1[e * H_ + n0 + wc * 64 + n * 16 + cix];
  #pragma unroll
  for (int rr = 0; rr < 4; ++rr) {
    if (wr == (rr >> 1)) {
      const int mb = (rr & 1) * 4;
      #pragma unroll
      for (int m = 0; m < 4; ++m)
        #pragma unroll
        for (int n = 0; n < 4; ++n)
          #pragma unroll
          for (int j = 0; j < 4; ++j)
            SM[(m * 16 + rhi + j) * 264 + wc * 64 + n * 16 + cix] =
                f2h_bits(gelu_f(acc[mb + m][n][j] + bv[n]));
    }
    __syncthreads();
    {
      const int rl = tid >> 3, co = (tid & 7) * 32;
      const int gr = row0g + rr * 64 + rl;
      if (gr < rend) {
        u16* dst = &Hb[(size_t)gr * H_ + n0 + co];
        const u16* sp = &SM[rl * 264 + co];
        #pragma unroll
        for (int qq = 0; qq < 4; ++qq)
          *(u16x8*)(dst + qq * 8) = *(const u16x8*)(sp + qq * 8);
      }
    }
    __syncthreads();
  }
}

// GEMM2: out[tok][n] += wslot * ( Hb[row][:] @ W2t[e][n][:]^T + b2[e][n] )
// 256x256 tile, K-split=2 (blockIdx.y), atomic combine. Grid NT256*4 x 2.
__global__ __launch_bounds__(512, 2) void k_gemm2(
    const u16* __restrict__ Hb, const u16* __restrict__ W2t,
    const float* __restrict__ b2, const int* __restrict__ offsets,
    const int* __restrict__ tmap, const int* __restrict__ atok,
    const float* __restrict__ wslot, float* __restrict__ out) {
  const int packed = tmap[blockIdx.x >> 2];
  if (packed < 0) return;
  const int e = packed >> 20;
  const int row0g = packed & 0xFFFFF;
  const int rend = offsets[e + 1];
  const int nt = blockIdx.x & 3;
  const int n0 = nt * 256;
  const int kbase = blockIdx.y * 2048;
  const int tid = threadIdx.x, lane = tid & 63, wid = tid >> 6;
  const int wr = wid >> 2, wc = wid & 3;
  const int Alim = (MAXR - 1) - row0g;
  __shared__ __align__(16) u16 SM[32768];
  f32x4 acc[8][4] = {};
  const u16* Ap = Hb + (size_t)row0g * H_ + kbase;
  const u16* Bp = W2t + (size_t)e * DOUT_ * H_ + (size_t)n0 * H_ + kbase;

  STG(H_, 0, 0, 8192);
  __syncthreads();
  for (int t = 0; t < 64; t += 2) {
    STG(H_, (t + 1) * 32, 16384, 24576);
    CMP(0, 8192);
    __syncthreads();
    if (t + 2 < 64) STG(H_, (t + 2) * 32, 0, 8192);
    CMP(16384, 24576);
    __syncthreads();
  }
  const int rhi = (lane >> 4) * 4, cix = lane & 15;
  const int first = (kbase == 0);
  float bv[4];
  #pragma unroll
  for (int n = 0; n < 4; ++n) bv[n] = b2[e * DOUT_ + n0 + wc * 64 + n * 16 + cix];
  #pragma unroll
  for (int m = 0; m < 8; ++m) {
    #pragma unroll
    for (int j = 0; j < 4; ++j) {
      int slot = row0g + wr * 128 + m * 16 + rhi + j;
      if (slot >= rend) continue;        // overhang into next expert's region
      float w = wslot[slot];
      if (w == 0.f) continue;            // padding slot
      int tok = atok[slot];
      float* orow = out + (size_t)tok * DOUT_ + n0;
      #pragma unroll
      for (int n = 0; n < 4; ++n) {
        int lc = wc * 64 + n * 16 + cix;
        float v = first ? w * (acc[m][n][j] + bv[n]) : w * acc[m][n][j];
        atomicAdd(&orow[lc], v);
      }
    }
  }
}

extern "C" void kernel_launch(void* const* d_in, const int* in_sizes, int n_in,
                              void* d_out, int out_size, void* d_ws, size_t ws_size,
                              hipStream_t stream) {
  const float* x  = (const float*)d_in[0];
  const float* Wg = (const float*)d_in[1];
  const float* bg = (const float*)d_in[2];
  const float* W1 = (const float*)d_in[3];
  const float* b1 = (const float*)d_in[4];
  const float* W2 = (const float*)d_in[5];
  const float* b2 = (const float*)d_in[6];
  float* out = (float*)d_out;

  char* ws = (char*)d_ws;
  int*   counts  = (int*)(ws + 0);
  int*   cursors = (int*)(ws + 32);
  int*   offsets = (int*)(ws + 64);
  float* usage   = (float*)(ws + 128);
  int*   topi    = (int*)(ws + OFF_TOPI);
  float* topw    = (float*)(ws + OFF_TOPW);
  int*   atok    = (int*)(ws + OFF_ATOK);
  float* wslot   = (float*)(ws + OFF_WSL);
  int*   tmap    = (int*)(ws + OFF_TMAP);
  u16*   Xg      = (u16*)(ws + OFF_XG);
  u16*   W1t     = (u16*)(ws + OFF_W1T);
  u16*   W2t     = (u16*)(ws + OFF_W2T);
  u16*   Hb      = (u16*)(ws + OFF_HB);

  k_zero_out<<<B_ * DOUT_ / 1024, 256, 0, stream>>>(out);
  k_init<<<(MAXR + 255) / 256, 256, 0, stream>>>(atok, wslot, (int*)ws);
  k_gate<<<B_ / 4, 256, 0, stream>>>(x, Wg, bg, counts, usage, topi, topw);
  k_scan_aux<<<1, 64, 0, stream>>>(counts, offsets, usage, out + (size_t)B_ * DOUT_, tmap);
  k_scatter<<<B_ / 256, 256, 0, stream>>>(topi, topw, offsets, cursors, atok, wslot);
  k_gather<<<MAXR, 256, 0, stream>>>(x, atok, Xg);
  k_cvt_t<<<dim3(D_ / 64, H_ / 64, E_), 256, 0, stream>>>(W1, W1t, D_, H_);
  k_gemm1<<<NT256 * 16, 512, 0, stream>>>(Xg, W1t, b1, offsets, tmap, Hb);
  k_cvt_t<<<dim3(H_ / 64, DOUT_ / 64, E_), 256, 0, stream>>>(W2, W2t, H_, DOUT_);
  k_gemm2<<<dim3(NT256 * 4, 2), 512, 0, stream>>>(Hb, W2t, b2, offsets, tmap, atok, wslot, out);
}